// Round 12
// baseline (462.396 us; speedup 1.0000x reference)
//
#include <hip/hip_runtime.h>
#include <hip/hip_fp16.h>

#define N_NODES 25000   // = 25 * 1000 exactly, = 3125 * 8 exactly
#define E_EDGES 400000
#define KM 200      // message channels
#define RSA 256     // A-row stride in USHORTS: 200 bf16 A | pad | 20 fp32 x @u208 (512 B row)
#define RSB 256     // B-row stride BYTES: 200 int8 | pad | 20 fp16 x @208 | inv_p,inv_x @248
#define SCB 25      // scan blocks (1000 nodes each)

typedef float v2f __attribute__((ext_vector_type(2)));  // v_pk_fma_f32 operand
typedef __attribute__((ext_vector_type(8))) short bf16x8;          // MFMA A/B frag
typedef __attribute__((ext_vector_type(4))) float f32x4;           // MFMA C/D frag
typedef __attribute__((ext_vector_type(8))) unsigned short u16x8;  // packed W frags

__device__ __forceinline__ float2 h2f(unsigned u) {
  return __half22float2(*(const __half2*)&u);
}
__device__ __forceinline__ float4 i8x4f(unsigned u) {
  float4 f;
  f.x = (float)((int)(u << 24) >> 24);
  f.y = (float)((int)(u << 16) >> 24);
  f.z = (float)((int)(u << 8) >> 24);
  f.w = (float)((int)u >> 24);
  return f;
}
// bf16 round-half-up pack / unpack
__device__ __forceinline__ unsigned short f2bfr(float v) {
  unsigned u = __float_as_uint(v) + 0x8000u;
  return (unsigned short)(u >> 16);
}
__device__ __forceinline__ float bf2f(unsigned short h) {
  return __uint_as_float((unsigned)h << 16);
}
// unpack 8 bf16 (one uint4) -> 8 f32
__device__ __forceinline__ void bf8x(uint4 u, float* h) {
  h[0] = __uint_as_float(u.x << 16);
  h[1] = __uint_as_float(u.x & 0xffff0000u);
  h[2] = __uint_as_float(u.y << 16);
  h[3] = __uint_as_float(u.y & 0xffff0000u);
  h[4] = __uint_as_float(u.z << 16);
  h[5] = __uint_as_float(u.z & 0xffff0000u);
  h[6] = __uint_as_float(u.w << 16);
  h[7] = __uint_as_float(u.w & 0xffff0000u);
}

// h for 32 consecutive k of one edge: relu(A_bf16 + B_i8*invB)
__device__ __forceinline__ void h32c(const unsigned short* __restrict__ Ar,
                                     const unsigned char* __restrict__ Br,
                                     int k, float invB, float* hv) {
  uint4 a0 = *(const uint4*)(Ar + k);
  uint4 a1 = *(const uint4*)(Ar + k + 8);
  uint4 a2 = *(const uint4*)(Ar + k + 16);
  uint4 a3 = *(const uint4*)(Ar + k + 24);
  uint4 b0 = *(const uint4*)(Br + k);
  uint4 b1 = *(const uint4*)(Br + k + 16);
  float af[32];
  bf8x(a0, af); bf8x(a1, af + 8); bf8x(a2, af + 16); bf8x(a3, af + 24);
  unsigned bw[8] = {b0.x, b0.y, b0.z, b0.w, b1.x, b1.y, b1.z, b1.w};
#pragma unroll
  for (int q = 0; q < 8; q++) {
    float4 fq = i8x4f(bw[q]);
    hv[4 * q + 0] = fmaxf(af[4 * q + 0] + fq.x * invB, 0.f);
    hv[4 * q + 1] = fmaxf(af[4 * q + 1] + fq.y * invB, 0.f);
    hv[4 * q + 2] = fmaxf(af[4 * q + 2] + fq.z * invB, 0.f);
    hv[4 * q + 3] = fmaxf(af[4 * q + 3] + fq.w * invB, 0.f);
  }
}

// MFMA gate accumulation for one wave (64 edges): acc[rt][ct] = H(64x200)*W(200x20)
// HsW: this wave's LDS H-stage [64][40] ushorts (rows 80B, 16B-aligned).
// s_setprio(1) around the MFMA cluster (R11: -13 us, independent waves).
__device__ __forceinline__ void gate_mfma(
    const unsigned short* __restrict__ Ar, const unsigned char* __restrict__ Br,
    float invB, const u16x8* __restrict__ wmf,
    unsigned short* HsW, int lane, f32x4 acc[4][2]) {
  int frow = lane & 15, fko = (lane >> 4) * 8;
  unsigned short* myrow = HsW + lane * 40;
#pragma unroll
  for (int s = 0; s < 7; s++) {
    float hv[32];
    h32c(Ar, Br, s * 32, invB, hv);
    if (s == 6) {  // k = 192..223: only 192..199 valid
#pragma unroll
      for (int j = 8; j < 32; j++) hv[j] = 0.f;
    }
    unsigned up[16];
#pragma unroll
    for (int i = 0; i < 16; i++)
      up[i] = (unsigned)f2bfr(hv[2 * i]) | ((unsigned)f2bfr(hv[2 * i + 1]) << 16);
    *(uint4*)(myrow + 0) = make_uint4(up[0], up[1], up[2], up[3]);
    *(uint4*)(myrow + 8) = make_uint4(up[4], up[5], up[6], up[7]);
    *(uint4*)(myrow + 16) = make_uint4(up[8], up[9], up[10], up[11]);
    *(uint4*)(myrow + 24) = make_uint4(up[12], up[13], up[14], up[15]);
    bf16x8 bfr0 = *(const bf16x8*)&wmf[(s * 2 + 0) * 64 + lane];
    bf16x8 bfr1 = *(const bf16x8*)&wmf[(s * 2 + 1) * 64 + lane];
    __builtin_amdgcn_s_setprio(1);
#pragma unroll
    for (int rt = 0; rt < 4; rt++) {
      bf16x8 afr = *(const bf16x8*)(HsW + (rt * 16 + frow) * 40 + fko);
      acc[rt][0] = __builtin_amdgcn_mfma_f32_16x16x32_bf16(afr, bfr0, acc[rt][0], 0, 0, 0);
      acc[rt][1] = __builtin_amdgcn_mfma_f32_16x16x32_bf16(afr, bfr1, acc[rt][1], 0, 0, 0);
    }
    __builtin_amdgcn_s_setprio(0);
  }
}

// Segment sum, alignment-aware vectorized loads (uint4 = 8 bf16 per load).
// Summation remains in strict ascending-e order -> bitwise-identical result;
// only the load instruction count changes (~4x fewer on long ranges).
// Channel-plane bases are 16B-aligned, so (e & 7) == 0 <=> 16B-aligned address.
__device__ __forceinline__ float seg_sum_bf16(const unsigned short* __restrict__ g,
                                              int s, int t) {
  float v = 0.f;
  int e = s;
  int pre = (8 - (s & 7)) & 7;
  if (pre > t - s) pre = t - s;
  for (int i = 0; i < pre; i++) {
    v += bf2f(g[e]);
    e++;
  }
  for (; e + 8 <= t; e += 8) {
    uint4 u = *(const uint4*)(g + e);
    v += __uint_as_float(u.x << 16);
    v += __uint_as_float(u.x & 0xffff0000u);
    v += __uint_as_float(u.y << 16);
    v += __uint_as_float(u.y & 0xffff0000u);
    v += __uint_as_float(u.z << 16);
    v += __uint_as_float(u.z & 0xffff0000u);
    v += __uint_as_float(u.w << 16);
    v += __uint_as_float(u.w & 0xffff0000u);
  }
  for (; e < t; e++) v += bf2f(g[e]);
  return v;
}

// ---------------- sort-by-dst (CSR build, 25-block parallel scan) ----------------

__global__ void hist_kernel(const int* __restrict__ edges, int* __restrict__ hist) {
  int e = blockIdx.x * blockDim.x + threadIdx.x;
  if (e < E_EDGES) atomicAdd(&hist[edges[E_EDGES + e]], 1);
}

// stage A: per-block (1000-node) sums
__global__ void __launch_bounds__(1024) hist_bsum_kernel(
    const int* __restrict__ hist, int* __restrict__ bsum) {
  __shared__ int ws[16];
  int tid = threadIdx.x, lane = tid & 63, wv = tid >> 6;
  int idx = blockIdx.x * 1000 + tid;
  int h = (tid < 1000) ? hist[idx] : 0;
#pragma unroll
  for (int s = 1; s < 64; s <<= 1) h += __shfl_xor(h, s);
  if (lane == 0) ws[wv] = h;
  __syncthreads();
  if (tid < 16) {
    int v = ws[tid];
#pragma unroll
    for (int s = 1; s < 16; s <<= 1) v += __shfl_xor(v, s);
    if (tid == 0) bsum[blockIdx.x] = v;
  }
}

// stage B: scan the 25 block sums (lane-scan) + W fragment packing on the side.
__global__ void __launch_bounds__(1024) scan_tiny_kernel(
    const int* __restrict__ bsum, int* __restrict__ boff,
    const float* __restrict__ hWm2, const float* __restrict__ oWm2,
    u16x8* __restrict__ wmfh, u16x8* __restrict__ wmfo) {
  int tid = threadIdx.x;
  if (tid < 64) {
    int v = (tid < SCB) ? bsum[tid] : 0;
    int incl = v;
#pragma unroll
    for (int s = 1; s < 32; s <<= 1) {
      int o = __shfl_up(incl, s);
      if ((tid & 63) >= s) incl += o;
    }
    if (tid < SCB) boff[tid] = incl - v;  // exclusive
  }
  if (tid >= 128 && tid < 128 + 896) {
    int pt = tid - 128;
    int st = pt >> 7;       // step 0..6
    int r = pt & 127;
    int l = r & 63;
    int c = ((r >> 6) << 4) + (l & 15);
    int k0 = st * 32 + ((l >> 4) << 3);
    u16x8 ph, po;
#pragma unroll
    for (int j = 0; j < 8; j++) {
      int k = k0 + j;
      bool ok = (c < 20) && (k < 200);
      ph[j] = ok ? (short)f2bfr(hWm2[k * 20 + c]) : (short)0;
      po[j] = ok ? (short)f2bfr(oWm2[k * 20 + c]) : (short)0;
    }
    wmfh[pt] = ph;
    wmfo[pt] = po;
  }
}

// stage C: per-block exclusive scan, fill off/cursor
__global__ void __launch_bounds__(1024) scan_fill_kernel(
    const int* __restrict__ hist, const int* __restrict__ boff,
    int* __restrict__ off, int* __restrict__ cursor) {
  __shared__ int ws[16];
  int tid = threadIdx.x, lane = tid & 63, wv = tid >> 6;
  int idx = blockIdx.x * 1000 + tid;
  int h = (tid < 1000) ? hist[idx] : 0;
  int incl = h;
#pragma unroll
  for (int s = 1; s < 64; s <<= 1) {
    int o = __shfl_up(incl, s);
    if (lane >= s) incl += o;
  }
  if (lane == 63) ws[wv] = incl;
  __syncthreads();
  if (tid < 16) {
    int t = ws[tid];
#pragma unroll
    for (int s = 1; s < 16; s <<= 1) {
      int o = __shfl_up(t, s);
      if (tid >= s) t += o;
    }
    ws[tid] = t;
  }
  __syncthreads();
  int wbase = (wv == 0) ? 0 : ws[wv - 1];
  int g = boff[blockIdx.x] + wbase + incl - h;  // exclusive global offset
  if (tid < 1000) {
    off[idx] = g;
    cursor[idx] = g;
    if (blockIdx.x == SCB - 1 && tid == 999) off[N_NODES] = g + h;  // == E
  }
}

// ---------------- per-layer kernels ----------------

// Fused: scatter (128 edges/block) + prep layer-d (8 nodes/block) + d_out zeroing.
__global__ void __launch_bounds__(256) scatter_prep_d_kernel(
    const int* __restrict__ edges, int* __restrict__ cursor, int2* __restrict__ se,
    const float* __restrict__ xin,
    const float* __restrict__ Wm1, const float* __restrict__ bm1,
    unsigned short* __restrict__ A2, unsigned char* __restrict__ Bq,
    float* __restrict__ xr, float* __restrict__ out) {
  int tid = threadIdx.x;
  if (tid < 8) out[blockIdx.x * 8 + tid] = 0.f;
  if (tid < 128) {
    int e = blockIdx.x * 128 + tid;
    int s = edges[e];
    int d = edges[E_EDGES + e];
    int pos = atomicAdd(&cursor[d], 1);
    se[pos] = make_int2(s, d);
  }
  __shared__ unsigned wbmaxu;
  if (tid == 0) wbmaxu = 0;
  __syncthreads();
  int k = tid;
  float wa = 0.f, wb = 0.f, bm = 0.f;
  if (k < KM) {
    bm = bm1[k];
    wa = Wm1[k];
    wb = Wm1[KM + k];
  }
  float mb = (k < KM) ? fabsf(wb) : 0.f;
#pragma unroll
  for (int s = 1; s < 64; s <<= 1) mb = fmaxf(mb, __shfl_xor(mb, s));
  if ((k & 63) == 0) atomicMax(&wbmaxu, __float_as_uint(mb));
  __syncthreads();
  float wbmax = fmaxf(__uint_as_float(wbmaxu), 1e-30f);
  int n0 = blockIdx.x * 8;
  for (int i = 0; i < 8; i++) {
    int n = n0 + i;
    float xv = xin[n];
    float bBound = fmaxf(fabsf(xv) * wbmax, 1e-30f);
    float xBound = fmaxf(fabsf(xv), 1e-30f);
    size_t rowA = (size_t)n * RSA;
    unsigned char* rb = Bq + (size_t)n * RSB;
    if (k == 0) {
      xr[n] = xv;
      ((float*)(A2 + rowA + 208))[0] = xv;
      ((__half*)(rb + 208))[0] = __float2half(xv * (32768.f / xBound));
      ((float*)(rb + 248))[0] = bBound / 127.f;
      ((float*)(rb + 248))[1] = xBound / 32768.f;
    }
    if (k < KM) {
      A2[rowA + k] = f2bfr(bm + xv * wa);
      rb[k] = (unsigned char)(signed char)lrintf(xv * wb * (127.f / bBound));
    }
  }
}

// CIN=1 edge kernel (1 thread/edge, 16-k tiles, unroll 2).
__global__ void __launch_bounds__(128) edge1_kernel(
    const int2* __restrict__ se,
    const unsigned short* __restrict__ A2, const unsigned char* __restrict__ Bq,
    const float* __restrict__ Wm2, const float* __restrict__ bm2,
    unsigned short* __restrict__ gd) {
  int e = blockIdx.x * 128 + threadIdx.x;  // grid exact: no bounds check
  int2 sd = se[e];
  const unsigned short* Ar = A2 + (size_t)sd.y * RSA;
  const unsigned char* Br = Bq + (size_t)sd.x * RSB;
  float invB = ((const float*)(Br + 248))[0];
  float g = bm2[0];
#pragma unroll 2
  for (int k = 0; k < 192; k += 16) {
    uint4 a01 = *(const uint4*)(Ar + k);
    uint4 a23 = *(const uint4*)(Ar + k + 8);
    uint4 braw = *(const uint4*)(Br + k);
    float af[16];
    bf8x(a01, af);
    bf8x(a23, af + 8);
    unsigned bw[4] = {braw.x, braw.y, braw.z, braw.w};
#pragma unroll
    for (int q = 0; q < 4; q++) {
      float4 fq = i8x4f(bw[q]);
      g += fmaxf(af[4 * q + 0] + fq.x * invB, 0.f) * Wm2[k + 4 * q + 0];
      g += fmaxf(af[4 * q + 1] + fq.y * invB, 0.f) * Wm2[k + 4 * q + 1];
      g += fmaxf(af[4 * q + 2] + fq.z * invB, 0.f) * Wm2[k + 4 * q + 2];
      g += fmaxf(af[4 * q + 3] + fq.w * invB, 0.f) * Wm2[k + 4 * q + 3];
    }
  }
  {  // tail k = 192..199
    uint4 a01 = *(const uint4*)(Ar + 192);
    uint2 braw = *(const uint2*)(Br + 192);
    float af[8];
    bf8x(a01, af);
    float4 f01 = i8x4f(braw.x);
    float4 f23 = i8x4f(braw.y);
    g += fmaxf(af[0] + f01.x * invB, 0.f) * Wm2[192];
    g += fmaxf(af[1] + f01.y * invB, 0.f) * Wm2[193];
    g += fmaxf(af[2] + f01.z * invB, 0.f) * Wm2[194];
    g += fmaxf(af[3] + f01.w * invB, 0.f) * Wm2[195];
    g += fmaxf(af[4] + f23.x * invB, 0.f) * Wm2[196];
    g += fmaxf(af[5] + f23.y * invB, 0.f) * Wm2[197];
    g += fmaxf(af[6] + f23.z * invB, 0.f) * Wm2[198];
    g += fmaxf(af[7] + f23.w * invB, 0.f) * Wm2[199];
  }
  float xa = ((const float*)(Ar + 208))[0];
  float invXb = ((const float*)(Br + 248))[1];
  float xb = __half2float(((const __half*)(Br + 208))[0]) * invXb;
  __builtin_nontemporal_store(f2bfr(g * (xa - xb)), gd + e);
}

// MFMA edge kernel, CIN=20: 128 threads = 2 independent waves, 64 edges each.
// Hs/Ds LDS aliased (never live simultaneously) -> 10240 B/block.
__global__ void __launch_bounds__(128, 4) edge_mfma20_kernel(
    const int2* __restrict__ se,
    const unsigned short* __restrict__ A2, const unsigned char* __restrict__ Bq,
    const u16x8* __restrict__ wmf, const float* __restrict__ bm2,
    unsigned short* __restrict__ gd) {
  __shared__ __align__(16) unsigned short Hs[2][64][40];
  int tid = threadIdx.x, w = tid >> 6, lane = tid & 63;
  float* Ds = (float*)&Hs[w][0][0];  // [64][20] f32, aliases this wave's H half
  int e = blockIdx.x * 128 + w * 64 + lane;
  int2 sd = se[e];
  const unsigned short* Ar = A2 + (size_t)sd.y * RSA;
  const unsigned char* Br = Bq + (size_t)sd.x * RSB;
  float invB = ((const float*)(Br + 248))[0];
  f32x4 acc[4][2];
  f32x4 zero = {0.f, 0.f, 0.f, 0.f};
#pragma unroll
  for (int rt = 0; rt < 4; rt++) {
    acc[rt][0] = zero;
    acc[rt][1] = zero;
  }
  gate_mfma(Ar, Br, invB, wmf, &Hs[w][0][0], lane, acc);
  // D transpose: tile (rt,ct), reg r -> edge rt*16+(lane>>4)*4+r, ch ct*16+(lane&15)
#pragma unroll
  for (int rt = 0; rt < 4; rt++) {
    int eb = rt * 16 + (lane >> 4) * 4;
    int ch = lane & 15;
#pragma unroll
    for (int r = 0; r < 4; r++) Ds[(eb + r) * 20 + ch] = acc[rt][0][r];
    if (ch < 4) {
#pragma unroll
      for (int r = 0; r < 4; r++) Ds[(eb + r) * 20 + 16 + ch] = acc[rt][1][r];
    }
  }
  // per-edge x-diff epilogue, gate = Ds + bm2
  float invXb = ((const float*)(Br + 248))[1];
  const __half* xtb = (const __half*)(Br + 208);
  const float* Ax = (const float*)(Ar + 208);
  unsigned wxb[10];
  {
    uint4 s0 = *(const uint4*)(xtb);
    uint4 s1 = *(const uint4*)(xtb + 8);
    uint2 s2 = *(const uint2*)(xtb + 16);
    wxb[0] = s0.x; wxb[1] = s0.y; wxb[2] = s0.z; wxb[3] = s0.w;
    wxb[4] = s1.x; wxb[5] = s1.y; wxb[6] = s1.z; wxb[7] = s1.w;
    wxb[8] = s2.x; wxb[9] = s2.y;
  }
#pragma unroll
  for (int i = 0; i < 10; i++) {
    float2 gp = *(const float2*)&Ds[lane * 20 + 2 * i];
    float gx = gp.x + bm2[2 * i];
    float gy = gp.y + bm2[2 * i + 1];
    float2 xa = *(const float2*)(Ax + 2 * i);
    float2 fb = h2f(wxb[i]);
    __builtin_nontemporal_store(f2bfr(gx * (xa.x - fb.x * invXb)),
                                gd + (size_t)(2 * i) * E_EDGES + e);
    __builtin_nontemporal_store(f2bfr(gy * (xa.y - fb.y * invXb)),
                                gd + (size_t)(2 * i + 1) * E_EDGES + e);
  }
}

// MFMA final-layer edge kernel + node-term fold (same Hs/Ds aliasing).
__global__ void __launch_bounds__(128, 4) edge_final_mfma_kernel(
    const int2* __restrict__ se,
    const unsigned short* __restrict__ A2, const unsigned char* __restrict__ Bq,
    const u16x8* __restrict__ wmf, const float* __restrict__ bm2,
    const float* __restrict__ W2,
    const int* __restrict__ off, const float* __restrict__ xrp,
    const float* __restrict__ W1, const float* __restrict__ b1,
    const float* __restrict__ b2, float* __restrict__ out) {
  __shared__ __align__(16) unsigned short Hs[2][64][40];
  int tid = threadIdx.x, w = tid >> 6, lane = tid & 63;
  float* Ds = (float*)&Hs[w][0][0];
  int e = blockIdx.x * 128 + w * 64 + lane;
  int2 sd = se[e];
  int dst = sd.y;
  const unsigned short* Ar = A2 + (size_t)dst * RSA;
  const unsigned char* Br = Bq + (size_t)sd.x * RSB;
  float invB = ((const float*)(Br + 248))[0];
  f32x4 acc[4][2];
  f32x4 zero = {0.f, 0.f, 0.f, 0.f};
#pragma unroll
  for (int rt = 0; rt < 4; rt++) {
    acc[rt][0] = zero;
    acc[rt][1] = zero;
  }
  gate_mfma(Ar, Br, invB, wmf, &Hs[w][0][0], lane, acc);
#pragma unroll
  for (int rt = 0; rt < 4; rt++) {
    int eb = rt * 16 + (lane >> 4) * 4;
    int ch = lane & 15;
#pragma unroll
    for (int r = 0; r < 4; r++) Ds[(eb + r) * 20 + ch] = acc[rt][0][r];
    if (ch < 4) {
#pragma unroll
      for (int r = 0; r < 4; r++) Ds[(eb + r) * 20 + 16 + ch] = acc[rt][1][r];
    }
  }
  // per-edge scalar contribution: dot(gate * xd, W2)
  float invXb = ((const float*)(Br + 248))[1];
  const __half* xtb = (const __half*)(Br + 208);
  const float* Ax = (const float*)(Ar + 208);
  unsigned wxb[10];
  {
    uint4 s0 = *(const uint4*)(xtb);
    uint4 s1 = *(const uint4*)(xtb + 8);
    uint2 s2 = *(const uint2*)(xtb + 16);
    wxb[0] = s0.x; wxb[1] = s0.y; wxb[2] = s0.z; wxb[3] = s0.w;
    wxb[4] = s1.x; wxb[5] = s1.y; wxb[6] = s1.z; wxb[7] = s1.w;
    wxb[8] = s2.x; wxb[9] = s2.y;
  }
  float sv = 0.f;
#pragma unroll
  for (int i = 0; i < 10; i++) {
    float2 gp = *(const float2*)&Ds[lane * 20 + 2 * i];
    float gx = gp.x + bm2[2 * i];
    float gy = gp.y + bm2[2 * i + 1];
    float2 xa = *(const float2*)(Ax + 2 * i);
    float2 fb = h2f(wxb[i]);
    sv += gx * (xa.x - fb.x * invXb) * W2[2 * i] +
          gy * (xa.y - fb.y * invXb) * W2[2 * i + 1];
  }
  // wave-level segmented sum over equal-dst runs (dst-sorted), 1 atomic/run
  bool seg[6];
#pragma unroll
  for (int i = 0; i < 6; i++) {
    int s = 1 << i;
    int od = __shfl_up(dst, s);
    seg[i] = (lane >= s) && (od == dst);
  }
#pragma unroll
  for (int i = 0; i < 6; i++) {
    float o = __shfl_up(sv, 1 << i);
    if (seg[i]) sv += o;
  }
  int dn = __shfl_down(dst, 1);
  bool is_last = (lane == 63) || (dn != dst);
  if (is_last) atomicAdd(out + dst, sv);
  // node-term fold: 8 nodes/block, grid 3125 = N/8
  if (tid < 8) {
    int n = blockIdx.x * 8 + tid;
    float deg = (float)(off[n + 1] - off[n]);
    float v = b1[0] + deg * b2[0];
    const float* xp = xrp + (size_t)n * 20;
#pragma unroll
    for (int c = 0; c < 20; c++) v += xp[c] * W1[c];
    atomicAdd(out + n, v);
  }
}

// afp1: after layer-d edge (gd 1-channel bf16). Per block: 8 nodes.
__global__ void __launch_bounds__(256) afp1_kernel(
    const unsigned short* __restrict__ gd, const int* __restrict__ off,
    const float* __restrict__ xrp,
    const float* __restrict__ W1, const float* __restrict__ b1,
    const float* __restrict__ W2, const float* __restrict__ b2,
    const float* __restrict__ Wm1n, const float* __restrict__ bm1n,
    unsigned short* __restrict__ A2, unsigned char* __restrict__ Bq,
    float* __restrict__ xrn) {
  __shared__ float ag[8], xp[8], degs[8];
  __shared__ float xv[8][21];
  __shared__ unsigned bmaxu[8];
  __shared__ float xmaxs[8];
  int tid = threadIdx.x;
  int n0 = blockIdx.x * 8;
  if (tid < 8) {
    bmaxu[tid] = 0;
    int n = n0 + tid;
    int s = off[n], t = off[n + 1];
    ag[tid] = seg_sum_bf16(gd, s, t);
    xp[tid] = xrp[n];
    degs[tid] = (float)(t - s);
  }
  __syncthreads();
  if (tid < 160) {
    int o = tid >> 3, nl = tid & 7;
    float v = b1[o] + degs[nl] * b2[o] + ag[nl] * W2[o] + xp[nl] * W1[o];
    float r = fmaxf(v, 0.f);
    xv[nl][o] = r;
    xrn[(n0 + nl) * 20 + o] = r;
  }
  __syncthreads();
  if (tid < 8) {
    float m = 0.f;
#pragma unroll
    for (int c = 0; c < 20; c++) m = fmaxf(m, xv[tid][c]);
    xmaxs[tid] = fmaxf(m, 1e-30f);
  }
  int k = tid;
  float aa[8], bb[8];
  if (k < KM) {
    v2f wab[20];
    float bm = bm1n[k];
#pragma unroll
    for (int c = 0; c < 20; c++) {
      wab[c].x = Wm1n[c * KM + k];
      wab[c].y = Wm1n[(20 + c) * KM + k];
    }
#pragma unroll
    for (int nl = 0; nl < 8; nl++) {
      v2f acc;
      acc.x = bm;
      acc.y = 0.f;
#pragma unroll
      for (int c = 0; c < 20; c++) {
        v2f xc;
        xc.x = xv[nl][c];
        xc.y = xv[nl][c];
        acc += xc * wab[c];
      }
      aa[nl] = acc.x;
      bb[nl] = acc.y;
    }
  }
  float mxb[8];
#pragma unroll
  for (int nl = 0; nl < 8; nl++) mxb[nl] = (k < KM) ? fabsf(bb[nl]) : 0.f;
#pragma unroll
  for (int s = 1; s < 64; s <<= 1) {
#pragma unroll
    for (int nl = 0; nl < 8; nl++) mxb[nl] = fmaxf(mxb[nl], __shfl_xor(mxb[nl], s));
  }
  if ((tid & 63) == 0) {
#pragma unroll
    for (int nl = 0; nl < 8; nl++) atomicMax(&bmaxu[nl], __float_as_uint(mxb[nl]));
  }
  __syncthreads();
  if (k < KM) {
#pragma unroll
    for (int nl = 0; nl < 8; nl++) {
      float bmax = fmaxf(__uint_as_float(bmaxu[nl]), 1e-30f);
      float xmax = xmaxs[nl];
      unsigned short* Au = A2 + (size_t)(n0 + nl) * RSA;
      unsigned char* rb = Bq + (size_t)(n0 + nl) * RSB;
      Au[k] = f2bfr(aa[nl]);
      rb[k] = (unsigned char)(signed char)lrintf(bb[nl] * (127.f / bmax));
      if (k < 20) {
        ((float*)(Au + 208))[k] = xv[nl][k];
        ((__half*)(rb + 208))[k] = __float2half(xv[nl][k] * (32768.f / xmax));
      }
      if (k == 0) {
        ((float*)(rb + 248))[0] = bmax / 127.f;
        ((float*)(rb + 248))[1] = xmax / 32768.f;
      }
    }
  }
}

// afp20: after a hidden edge (gd 20-channel bf16). Same 3 phases, CIN=20.
__global__ void __launch_bounds__(256) afp20_kernel(
    const unsigned short* __restrict__ gd, const int* __restrict__ off,
    const float* __restrict__ xrp,
    const float* __restrict__ W1, const float* __restrict__ b1,
    const float* __restrict__ W2, const float* __restrict__ b2,
    const float* __restrict__ Wm1n, const float* __restrict__ bm1n,
    unsigned short* __restrict__ A2, unsigned char* __restrict__ Bq,
    float* __restrict__ xrn) {
  __shared__ float ag[8][21], xp[8][21], xv[8][21], degs[8];
  __shared__ unsigned bmaxu[8];
  __shared__ float xmaxs[8];
  int tid = threadIdx.x;
  int n0 = blockIdx.x * 8;
  if (tid < 8) bmaxu[tid] = 0;
  if (tid < 160) {
    int c = tid >> 3, nl = tid & 7;
    int n = n0 + nl;
    int s = off[n], t = off[n + 1];
    ag[nl][c] = seg_sum_bf16(gd + (size_t)c * E_EDGES, s, t);
    xp[nl][c] = xrp[n * 20 + c];
    if (c == 0) degs[nl] = (float)(t - s);
  }
  __syncthreads();
  if (tid < 160) {
    int o = tid >> 3, nl = tid & 7;
    float v = b1[o] + degs[nl] * b2[o];
#pragma unroll
    for (int c = 0; c < 20; c++) {
      v += ag[nl][c] * W2[c * 20 + o] + xp[nl][c] * W1[c * 20 + o];
    }
    float r = fmaxf(v, 0.f);
    xv[nl][o] = r;
    xrn[(n0 + nl) * 20 + o] = r;
  }
  __syncthreads();
  if (tid < 8) {
    float m = 0.f;
#pragma unroll
    for (int c = 0; c < 20; c++) m = fmaxf(m, xv[tid][c]);
    xmaxs[tid] = fmaxf(m, 1e-30f);
  }
  int k = tid;
  float aa[8], bb[8];
  if (k < KM) {
    v2f wab[20];
    float bm = bm1n[k];
#pragma unroll
    for (int c = 0; c < 20; c++) {
      wab[c].x = Wm1n[c * KM + k];
      wab[c].y = Wm1n[(20 + c) * KM + k];
    }
#pragma unroll
    for (int nl = 0; nl < 8; nl++) {
      v2f acc;
      acc.x = bm;
      acc.y = 0.f;
#pragma unroll
      for (int c = 0; c < 20; c++) {
        v2f xc;
        xc.x = xv[nl][c];
        xc.y = xv[nl][c];
        acc += xc * wab[c];
      }
      aa[nl] = acc.x;
      bb[nl] = acc.y;
    }
  }
  float mxb[8];
#pragma unroll
  for (int nl = 0; nl < 8; nl++) mxb[nl] = (k < KM) ? fabsf(bb[nl]) : 0.f;
#pragma unroll
  for (int s = 1; s < 64; s <<= 1) {
#pragma unroll
    for (int nl = 0; nl < 8; nl++) mxb[nl] = fmaxf(mxb[nl], __shfl_xor(mxb[nl], s));
  }
  if ((tid & 63) == 0) {
#pragma unroll
    for (int nl = 0; nl < 8; nl++) atomicMax(&bmaxu[nl], __float_as_uint(mxb[nl]));
  }
  __syncthreads();
  if (k < KM) {
#pragma unroll
    for (int nl = 0; nl < 8; nl++) {
      float bmax = fmaxf(__uint_as_float(bmaxu[nl]), 1e-30f);
      float xmax = xmaxs[nl];
      unsigned short* Au = A2 + (size_t)(n0 + nl) * RSA;
      unsigned char* rb = Bq + (size_t)(n0 + nl) * RSB;
      Au[k] = f2bfr(aa[nl]);
      rb[k] = (unsigned char)(signed char)lrintf(bb[nl] * (127.f / bmax));
      if (k < 20) {
        ((float*)(Au + 208))[k] = xv[nl][k];
        ((__half*)(rb + 208))[k] = __float2half(xv[nl][k] * (32768.f / xmax));
      }
      if (k == 0) {
        ((float*)(rb + 248))[0] = bmax / 127.f;
        ((float*)(rb + 248))[1] = xmax / 32768.f;
      }
    }
  }
}

// ---------------- launch ----------------

extern "C" void kernel_launch(void* const* d_in, const int* in_sizes, int n_in,
                              void* d_out, int out_size, void* d_ws, size_t ws_size,
                              hipStream_t stream) {
  const float* features = (const float*)d_in[0];
  const int* edges = (const int*)d_in[1];
  // d_in[2] = weights (unused by reference)

  const float *dW1 = (const float*)d_in[3], *db1 = (const float*)d_in[4],
              *dWm1 = (const float*)d_in[5], *dbm1 = (const float*)d_in[6],
              *dWm2 = (const float*)d_in[7], *dbm2 = (const float*)d_in[8],
              *dW2 = (const float*)d_in[9], *db2 = (const float*)d_in[10];
  const float *hW1 = (const float*)d_in[11], *hb1 = (const float*)d_in[12],
              *hWm1 = (const float*)d_in[13], *hbm1 = (const float*)d_in[14],
              *hWm2 = (const float*)d_in[15], *hbm2 = (const float*)d_in[16],
              *hW2 = (const float*)d_in[17], *hb2 = (const float*)d_in[18];
  const float *oW1 = (const float*)d_in[19], *ob1 = (const float*)d_in[20],
              *oWm1 = (const float*)d_in[21], *obm1 = (const float*)d_in[22],
              *oWm2 = (const float*)d_in[23], *obm2 = (const float*)d_in[24],
              *oW2 = (const float*)d_in[25], *ob2 = (const float*)d_in[26];

  // workspace layout (float units)
  float* fws = (float*)d_ws;
  size_t o = 0;
  unsigned short* A2 = (unsigned short*)(fws + o); o += (size_t)N_NODES * (RSA / 2);
  unsigned char* Bq = (unsigned char*)(fws + o);   o += (size_t)N_NODES * RSB / 4;
  unsigned short* gd = (unsigned short*)(fws + o); o += (size_t)20 * E_EDGES / 2;
  float* xrA = fws + o;                            o += (size_t)N_NODES * 20;
  float* xrB = fws + o;                            o += (size_t)N_NODES * 20;
  u16x8* wmfh = (u16x8*)(fws + o);                 o += 3584;  // 896 * 16 B
  u16x8* wmfo = (u16x8*)(fws + o);                 o += 3584;
  int* ip = (int*)(fws + o);
  int* hist = ip;   ip += N_NODES;
  int* off = ip;    ip += N_NODES + 4;
  int* cursor = ip; ip += N_NODES;
  int* bsum = ip;   ip += 32;
  int* boff = ip;   ip += 32;
  int2* se = (int2*)ip;

  const int B256 = 256;
  const int EDGE_G = E_EDGES / 128;  // 3125, exact
  const int NODE8_G = N_NODES / 8;   // 3125, exact

  // build dst-sorted edge list + CSR offsets (recomputed every launch)
  (void)hipMemsetAsync(hist, 0, N_NODES * sizeof(int), stream);
  hist_kernel<<<(E_EDGES + B256 - 1) / B256, B256, 0, stream>>>(edges, hist);
  hist_bsum_kernel<<<SCB, 1024, 0, stream>>>(hist, bsum);
  scan_tiny_kernel<<<1, 1024, 0, stream>>>(bsum, boff, hWm2, oWm2, wmfh, wmfo);
  scan_fill_kernel<<<SCB, 1024, 0, stream>>>(hist, boff, off, cursor);

  // layer d: 1 -> 20 (scatter + d_out zeroing fused into prep)
  scatter_prep_d_kernel<<<NODE8_G, B256, 0, stream>>>(edges, cursor, se, features,
                                                      dWm1, dbm1, A2, Bq, xrA,
                                                      (float*)d_out);
  edge1_kernel<<<EDGE_G, 128, 0, stream>>>(se, A2, Bq, dWm2, dbm2, gd);
  afp1_kernel<<<NODE8_G, B256, 0, stream>>>(gd, off, xrA, dW1, db1, dW2, db2,
                                            hWm1, hbm1, A2, Bq, xrB);

  // hidden1
  edge_mfma20_kernel<<<EDGE_G, 128, 0, stream>>>(se, A2, Bq, wmfh, hbm2, gd);
  afp20_kernel<<<NODE8_G, B256, 0, stream>>>(gd, off, xrB, hW1, hb1, hW2, hb2,
                                             hWm1, hbm1, A2, Bq, xrA);
  // hidden2
  edge_mfma20_kernel<<<EDGE_G, 128, 0, stream>>>(se, A2, Bq, wmfh, hbm2, gd);
  afp20_kernel<<<NODE8_G, B256, 0, stream>>>(gd, off, xrA, hW1, hb1, hW2, hb2,
                                             hWm1, hbm1, A2, Bq, xrB);
  // hidden3 -> preps output layer (oWm1)
  edge_mfma20_kernel<<<EDGE_G, 128, 0, stream>>>(se, A2, Bq, wmfh, hbm2, gd);
  afp20_kernel<<<NODE8_G, B256, 0, stream>>>(gd, off, xrB, hW1, hb1, hW2, hb2,
                                             oWm1, obm1, A2, Bq, xrA);
  // output layer: 20 -> 1, gd-free (scalar atomics into d_out) + node terms fused
  edge_final_mfma_kernel<<<EDGE_G, 128, 0, stream>>>(se, A2, Bq, wmfo, obm2, oW2,
                                                     off, xrA, oW1, ob1, ob2,
                                                     (float*)d_out);
}

// Round 13
// 449.227 us; speedup vs baseline: 1.0293x; 1.0293x over previous
//
#include <hip/hip_runtime.h>
#include <hip/hip_fp16.h>

#define N_NODES 25000   // = 25 * 1000 exactly, = 3125 * 8 exactly
#define E_EDGES 400000
#define KM 200      // message channels
#define RSA 256     // A-row stride in USHORTS: 200 bf16 A | pad | 20 fp32 x @u208 (512 B row)
#define RSB 256     // B-row stride BYTES: 200 int8 | pad | 20 fp16 x @208 | inv_p,inv_x @248
#define SCB 25      // scan blocks (1000 nodes each)

typedef float v2f __attribute__((ext_vector_type(2)));  // v_pk_fma_f32 operand
typedef __attribute__((ext_vector_type(8))) short bf16x8;          // MFMA A/B frag
typedef __attribute__((ext_vector_type(4))) float f32x4;           // MFMA C/D frag
typedef __attribute__((ext_vector_type(8))) unsigned short u16x8;  // packed W frags

__device__ __forceinline__ float2 h2f(unsigned u) {
  return __half22float2(*(const __half2*)&u);
}
__device__ __forceinline__ float4 i8x4f(unsigned u) {
  float4 f;
  f.x = (float)((int)(u << 24) >> 24);
  f.y = (float)((int)(u << 16) >> 24);
  f.z = (float)((int)(u << 8) >> 24);
  f.w = (float)((int)u >> 24);
  return f;
}
// bf16 round-half-up pack / unpack
__device__ __forceinline__ unsigned short f2bfr(float v) {
  unsigned u = __float_as_uint(v) + 0x8000u;
  return (unsigned short)(u >> 16);
}
__device__ __forceinline__ float bf2f(unsigned short h) {
  return __uint_as_float((unsigned)h << 16);
}
// unpack 8 bf16 (one uint4) -> 8 f32
__device__ __forceinline__ void bf8x(uint4 u, float* h) {
  h[0] = __uint_as_float(u.x << 16);
  h[1] = __uint_as_float(u.x & 0xffff0000u);
  h[2] = __uint_as_float(u.y << 16);
  h[3] = __uint_as_float(u.y & 0xffff0000u);
  h[4] = __uint_as_float(u.z << 16);
  h[5] = __uint_as_float(u.z & 0xffff0000u);
  h[6] = __uint_as_float(u.w << 16);
  h[7] = __uint_as_float(u.w & 0xffff0000u);
}

// h for 32 consecutive k of one edge: relu(A_bf16 + B_i8*invB)
__device__ __forceinline__ void h32c(const unsigned short* __restrict__ Ar,
                                     const unsigned char* __restrict__ Br,
                                     int k, float invB, float* hv) {
  uint4 a0 = *(const uint4*)(Ar + k);
  uint4 a1 = *(const uint4*)(Ar + k + 8);
  uint4 a2 = *(const uint4*)(Ar + k + 16);
  uint4 a3 = *(const uint4*)(Ar + k + 24);
  uint4 b0 = *(const uint4*)(Br + k);
  uint4 b1 = *(const uint4*)(Br + k + 16);
  float af[32];
  bf8x(a0, af); bf8x(a1, af + 8); bf8x(a2, af + 16); bf8x(a3, af + 24);
  unsigned bw[8] = {b0.x, b0.y, b0.z, b0.w, b1.x, b1.y, b1.z, b1.w};
#pragma unroll
  for (int q = 0; q < 8; q++) {
    float4 fq = i8x4f(bw[q]);
    hv[4 * q + 0] = fmaxf(af[4 * q + 0] + fq.x * invB, 0.f);
    hv[4 * q + 1] = fmaxf(af[4 * q + 1] + fq.y * invB, 0.f);
    hv[4 * q + 2] = fmaxf(af[4 * q + 2] + fq.z * invB, 0.f);
    hv[4 * q + 3] = fmaxf(af[4 * q + 3] + fq.w * invB, 0.f);
  }
}

// MFMA gate accumulation for one wave (64 edges): acc[rt][ct] = H(64x200)*W(200x20)
// HsW: this wave's LDS H-stage [64][40] ushorts (rows 80B, 16B-aligned).
// s_setprio(1) around the MFMA cluster (R11: -13 us, independent waves).
__device__ __forceinline__ void gate_mfma(
    const unsigned short* __restrict__ Ar, const unsigned char* __restrict__ Br,
    float invB, const u16x8* __restrict__ wmf,
    unsigned short* HsW, int lane, f32x4 acc[4][2]) {
  int frow = lane & 15, fko = (lane >> 4) * 8;
  unsigned short* myrow = HsW + lane * 40;
#pragma unroll
  for (int s = 0; s < 7; s++) {
    float hv[32];
    h32c(Ar, Br, s * 32, invB, hv);
    if (s == 6) {  // k = 192..223: only 192..199 valid
#pragma unroll
      for (int j = 8; j < 32; j++) hv[j] = 0.f;
    }
    unsigned up[16];
#pragma unroll
    for (int i = 0; i < 16; i++)
      up[i] = (unsigned)f2bfr(hv[2 * i]) | ((unsigned)f2bfr(hv[2 * i + 1]) << 16);
    *(uint4*)(myrow + 0) = make_uint4(up[0], up[1], up[2], up[3]);
    *(uint4*)(myrow + 8) = make_uint4(up[4], up[5], up[6], up[7]);
    *(uint4*)(myrow + 16) = make_uint4(up[8], up[9], up[10], up[11]);
    *(uint4*)(myrow + 24) = make_uint4(up[12], up[13], up[14], up[15]);
    bf16x8 bfr0 = *(const bf16x8*)&wmf[(s * 2 + 0) * 64 + lane];
    bf16x8 bfr1 = *(const bf16x8*)&wmf[(s * 2 + 1) * 64 + lane];
    __builtin_amdgcn_s_setprio(1);
#pragma unroll
    for (int rt = 0; rt < 4; rt++) {
      bf16x8 afr = *(const bf16x8*)(HsW + (rt * 16 + frow) * 40 + fko);
      acc[rt][0] = __builtin_amdgcn_mfma_f32_16x16x32_bf16(afr, bfr0, acc[rt][0], 0, 0, 0);
      acc[rt][1] = __builtin_amdgcn_mfma_f32_16x16x32_bf16(afr, bfr1, acc[rt][1], 0, 0, 0);
    }
    __builtin_amdgcn_s_setprio(0);
  }
}

// Segment sum with batched loads: bitwise-identical to the naive loop.
__device__ __forceinline__ float seg_sum_bf16(const unsigned short* __restrict__ g,
                                              int s, int t) {
  float v = 0.f;
  int e = s;
  int t8 = s + ((t - s) & ~7);
  for (; e < t8; e += 8) {
    unsigned short u0 = g[e + 0], u1 = g[e + 1], u2 = g[e + 2], u3 = g[e + 3];
    unsigned short u4 = g[e + 4], u5 = g[e + 5], u6 = g[e + 6], u7 = g[e + 7];
    v += bf2f(u0); v += bf2f(u1); v += bf2f(u2); v += bf2f(u3);
    v += bf2f(u4); v += bf2f(u5); v += bf2f(u6); v += bf2f(u7);
  }
  int t2 = s + ((t - s) & ~1);
  for (; e < t2; e += 2) {
    unsigned short u0 = g[e + 0], u1 = g[e + 1];
    v += bf2f(u0); v += bf2f(u1);
  }
  if (e < t) v += bf2f(g[e]);
  return v;
}

// ---------------- sort-by-dst (CSR build, 25-block parallel scan) ----------------

__global__ void hist_kernel(const int* __restrict__ edges, int* __restrict__ hist) {
  int e = blockIdx.x * blockDim.x + threadIdx.x;
  if (e < E_EDGES) atomicAdd(&hist[edges[E_EDGES + e]], 1);
}

// stage A: per-block (1000-node) sums
__global__ void __launch_bounds__(1024) hist_bsum_kernel(
    const int* __restrict__ hist, int* __restrict__ bsum) {
  __shared__ int ws[16];
  int tid = threadIdx.x, lane = tid & 63, wv = tid >> 6;
  int idx = blockIdx.x * 1000 + tid;
  int h = (tid < 1000) ? hist[idx] : 0;
#pragma unroll
  for (int s = 1; s < 64; s <<= 1) h += __shfl_xor(h, s);
  if (lane == 0) ws[wv] = h;
  __syncthreads();
  if (tid < 16) {
    int v = ws[tid];
#pragma unroll
    for (int s = 1; s < 16; s <<= 1) v += __shfl_xor(v, s);
    if (tid == 0) bsum[blockIdx.x] = v;
  }
}

// stage B: scan the 25 block sums (lane-scan) + W fragment packing on the side.
__global__ void __launch_bounds__(1024) scan_tiny_kernel(
    const int* __restrict__ bsum, int* __restrict__ boff,
    const float* __restrict__ hWm2, const float* __restrict__ oWm2,
    u16x8* __restrict__ wmfh, u16x8* __restrict__ wmfo) {
  int tid = threadIdx.x;
  if (tid < 64) {
    int v = (tid < SCB) ? bsum[tid] : 0;
    int incl = v;
#pragma unroll
    for (int s = 1; s < 32; s <<= 1) {
      int o = __shfl_up(incl, s);
      if ((tid & 63) >= s) incl += o;
    }
    if (tid < SCB) boff[tid] = incl - v;  // exclusive
  }
  if (tid >= 128 && tid < 128 + 896) {
    int pt = tid - 128;
    int st = pt >> 7;       // step 0..6
    int r = pt & 127;
    int l = r & 63;
    int c = ((r >> 6) << 4) + (l & 15);
    int k0 = st * 32 + ((l >> 4) << 3);
    u16x8 ph, po;
#pragma unroll
    for (int j = 0; j < 8; j++) {
      int k = k0 + j;
      bool ok = (c < 20) && (k < 200);
      ph[j] = ok ? (short)f2bfr(hWm2[k * 20 + c]) : (short)0;
      po[j] = ok ? (short)f2bfr(oWm2[k * 20 + c]) : (short)0;
    }
    wmfh[pt] = ph;
    wmfo[pt] = po;
  }
}

// stage C: per-block exclusive scan, fill off/cursor
__global__ void __launch_bounds__(1024) scan_fill_kernel(
    const int* __restrict__ hist, const int* __restrict__ boff,
    int* __restrict__ off, int* __restrict__ cursor) {
  __shared__ int ws[16];
  int tid = threadIdx.x, lane = tid & 63, wv = tid >> 6;
  int idx = blockIdx.x * 1000 + tid;
  int h = (tid < 1000) ? hist[idx] : 0;
  int incl = h;
#pragma unroll
  for (int s = 1; s < 64; s <<= 1) {
    int o = __shfl_up(incl, s);
    if (lane >= s) incl += o;
  }
  if (lane == 63) ws[wv] = incl;
  __syncthreads();
  if (tid < 16) {
    int t = ws[tid];
#pragma unroll
    for (int s = 1; s < 16; s <<= 1) {
      int o = __shfl_up(t, s);
      if (tid >= s) t += o;
    }
    ws[tid] = t;
  }
  __syncthreads();
  int wbase = (wv == 0) ? 0 : ws[wv - 1];
  int g = boff[blockIdx.x] + wbase + incl - h;  // exclusive global offset
  if (tid < 1000) {
    off[idx] = g;
    cursor[idx] = g;
    if (blockIdx.x == SCB - 1 && tid == 999) off[N_NODES] = g + h;  // == E
  }
}

// ---------------- per-layer kernels ----------------

// Fused: scatter (128 edges/block) + prep layer-d (8 nodes/block) + d_out zeroing.
__global__ void __launch_bounds__(256) scatter_prep_d_kernel(
    const int* __restrict__ edges, int* __restrict__ cursor, int2* __restrict__ se,
    const float* __restrict__ xin,
    const float* __restrict__ Wm1, const float* __restrict__ bm1,
    unsigned short* __restrict__ A2, unsigned char* __restrict__ Bq,
    float* __restrict__ xr, float* __restrict__ out) {
  int tid = threadIdx.x;
  if (tid < 8) out[blockIdx.x * 8 + tid] = 0.f;
  if (tid < 128) {
    int e = blockIdx.x * 128 + tid;
    int s = edges[e];
    int d = edges[E_EDGES + e];
    int pos = atomicAdd(&cursor[d], 1);
    se[pos] = make_int2(s, d);
  }
  __shared__ unsigned wbmaxu;
  if (tid == 0) wbmaxu = 0;
  __syncthreads();
  int k = tid;
  float wa = 0.f, wb = 0.f, bm = 0.f;
  if (k < KM) {
    bm = bm1[k];
    wa = Wm1[k];
    wb = Wm1[KM + k];
  }
  float mb = (k < KM) ? fabsf(wb) : 0.f;
#pragma unroll
  for (int s = 1; s < 64; s <<= 1) mb = fmaxf(mb, __shfl_xor(mb, s));
  if ((k & 63) == 0) atomicMax(&wbmaxu, __float_as_uint(mb));
  __syncthreads();
  float wbmax = fmaxf(__uint_as_float(wbmaxu), 1e-30f);
  int n0 = blockIdx.x * 8;
  for (int i = 0; i < 8; i++) {
    int n = n0 + i;
    float xv = xin[n];
    float bBound = fmaxf(fabsf(xv) * wbmax, 1e-30f);
    float xBound = fmaxf(fabsf(xv), 1e-30f);
    size_t rowA = (size_t)n * RSA;
    unsigned char* rb = Bq + (size_t)n * RSB;
    if (k == 0) {
      xr[n] = xv;
      ((float*)(A2 + rowA + 208))[0] = xv;
      ((__half*)(rb + 208))[0] = __float2half(xv * (32768.f / xBound));
      ((float*)(rb + 248))[0] = bBound / 127.f;
      ((float*)(rb + 248))[1] = xBound / 32768.f;
    }
    if (k < KM) {
      A2[rowA + k] = f2bfr(bm + xv * wa);
      rb[k] = (unsigned char)(signed char)lrintf(xv * wb * (127.f / bBound));
    }
  }
}

// CIN=1 edge kernel (1 thread/edge, 16-k tiles, unroll 2).
__global__ void __launch_bounds__(128) edge1_kernel(
    const int2* __restrict__ se,
    const unsigned short* __restrict__ A2, const unsigned char* __restrict__ Bq,
    const float* __restrict__ Wm2, const float* __restrict__ bm2,
    unsigned short* __restrict__ gd) {
  int e = blockIdx.x * 128 + threadIdx.x;  // grid exact: no bounds check
  int2 sd = se[e];
  const unsigned short* Ar = A2 + (size_t)sd.y * RSA;
  const unsigned char* Br = Bq + (size_t)sd.x * RSB;
  float invB = ((const float*)(Br + 248))[0];
  float g = bm2[0];
#pragma unroll 2
  for (int k = 0; k < 192; k += 16) {
    uint4 a01 = *(const uint4*)(Ar + k);
    uint4 a23 = *(const uint4*)(Ar + k + 8);
    uint4 braw = *(const uint4*)(Br + k);
    float af[16];
    bf8x(a01, af);
    bf8x(a23, af + 8);
    unsigned bw[4] = {braw.x, braw.y, braw.z, braw.w};
#pragma unroll
    for (int q = 0; q < 4; q++) {
      float4 fq = i8x4f(bw[q]);
      g += fmaxf(af[4 * q + 0] + fq.x * invB, 0.f) * Wm2[k + 4 * q + 0];
      g += fmaxf(af[4 * q + 1] + fq.y * invB, 0.f) * Wm2[k + 4 * q + 1];
      g += fmaxf(af[4 * q + 2] + fq.z * invB, 0.f) * Wm2[k + 4 * q + 2];
      g += fmaxf(af[4 * q + 3] + fq.w * invB, 0.f) * Wm2[k + 4 * q + 3];
    }
  }
  {  // tail k = 192..199
    uint4 a01 = *(const uint4*)(Ar + 192);
    uint2 braw = *(const uint2*)(Br + 192);
    float af[8];
    bf8x(a01, af);
    float4 f01 = i8x4f(braw.x);
    float4 f23 = i8x4f(braw.y);
    g += fmaxf(af[0] + f01.x * invB, 0.f) * Wm2[192];
    g += fmaxf(af[1] + f01.y * invB, 0.f) * Wm2[193];
    g += fmaxf(af[2] + f01.z * invB, 0.f) * Wm2[194];
    g += fmaxf(af[3] + f01.w * invB, 0.f) * Wm2[195];
    g += fmaxf(af[4] + f23.x * invB, 0.f) * Wm2[196];
    g += fmaxf(af[5] + f23.y * invB, 0.f) * Wm2[197];
    g += fmaxf(af[6] + f23.z * invB, 0.f) * Wm2[198];
    g += fmaxf(af[7] + f23.w * invB, 0.f) * Wm2[199];
  }
  float xa = ((const float*)(Ar + 208))[0];
  float invXb = ((const float*)(Br + 248))[1];
  float xb = __half2float(((const __half*)(Br + 208))[0]) * invXb;
  __builtin_nontemporal_store(f2bfr(g * (xa - xb)), gd + e);
}

// MFMA edge kernel, CIN=20: 128 threads = 2 independent waves, 64 edges each.
// Hs/Ds LDS aliased (never live simultaneously) -> 10240 B/block.
__global__ void __launch_bounds__(128, 4) edge_mfma20_kernel(
    const int2* __restrict__ se,
    const unsigned short* __restrict__ A2, const unsigned char* __restrict__ Bq,
    const u16x8* __restrict__ wmf, const float* __restrict__ bm2,
    unsigned short* __restrict__ gd) {
  __shared__ __align__(16) unsigned short Hs[2][64][40];
  int tid = threadIdx.x, w = tid >> 6, lane = tid & 63;
  float* Ds = (float*)&Hs[w][0][0];  // [64][20] f32, aliases this wave's H half
  int e = blockIdx.x * 128 + w * 64 + lane;
  int2 sd = se[e];
  const unsigned short* Ar = A2 + (size_t)sd.y * RSA;
  const unsigned char* Br = Bq + (size_t)sd.x * RSB;
  float invB = ((const float*)(Br + 248))[0];
  f32x4 acc[4][2];
  f32x4 zero = {0.f, 0.f, 0.f, 0.f};
#pragma unroll
  for (int rt = 0; rt < 4; rt++) {
    acc[rt][0] = zero;
    acc[rt][1] = zero;
  }
  gate_mfma(Ar, Br, invB, wmf, &Hs[w][0][0], lane, acc);
  // D transpose: tile (rt,ct), reg r -> edge rt*16+(lane>>4)*4+r, ch ct*16+(lane&15)
#pragma unroll
  for (int rt = 0; rt < 4; rt++) {
    int eb = rt * 16 + (lane >> 4) * 4;
    int ch = lane & 15;
#pragma unroll
    for (int r = 0; r < 4; r++) Ds[(eb + r) * 20 + ch] = acc[rt][0][r];
    if (ch < 4) {
#pragma unroll
      for (int r = 0; r < 4; r++) Ds[(eb + r) * 20 + 16 + ch] = acc[rt][1][r];
    }
  }
  // per-edge x-diff epilogue, gate = Ds + bm2
  float invXb = ((const float*)(Br + 248))[1];
  const __half* xtb = (const __half*)(Br + 208);
  const float* Ax = (const float*)(Ar + 208);
  unsigned wxb[10];
  {
    uint4 s0 = *(const uint4*)(xtb);
    uint4 s1 = *(const uint4*)(xtb + 8);
    uint2 s2 = *(const uint2*)(xtb + 16);
    wxb[0] = s0.x; wxb[1] = s0.y; wxb[2] = s0.z; wxb[3] = s0.w;
    wxb[4] = s1.x; wxb[5] = s1.y; wxb[6] = s1.z; wxb[7] = s1.w;
    wxb[8] = s2.x; wxb[9] = s2.y;
  }
#pragma unroll
  for (int i = 0; i < 10; i++) {
    float2 gp = *(const float2*)&Ds[lane * 20 + 2 * i];
    float gx = gp.x + bm2[2 * i];
    float gy = gp.y + bm2[2 * i + 1];
    float2 xa = *(const float2*)(Ax + 2 * i);
    float2 fb = h2f(wxb[i]);
    __builtin_nontemporal_store(f2bfr(gx * (xa.x - fb.x * invXb)),
                                gd + (size_t)(2 * i) * E_EDGES + e);
    __builtin_nontemporal_store(f2bfr(gy * (xa.y - fb.y * invXb)),
                                gd + (size_t)(2 * i + 1) * E_EDGES + e);
  }
}

// MFMA final-layer edge kernel + node-term fold (same Hs/Ds aliasing).
__global__ void __launch_bounds__(128, 4) edge_final_mfma_kernel(
    const int2* __restrict__ se,
    const unsigned short* __restrict__ A2, const unsigned char* __restrict__ Bq,
    const u16x8* __restrict__ wmf, const float* __restrict__ bm2,
    const float* __restrict__ W2,
    const int* __restrict__ off, const float* __restrict__ xrp,
    const float* __restrict__ W1, const float* __restrict__ b1,
    const float* __restrict__ b2, float* __restrict__ out) {
  __shared__ __align__(16) unsigned short Hs[2][64][40];
  int tid = threadIdx.x, w = tid >> 6, lane = tid & 63;
  float* Ds = (float*)&Hs[w][0][0];
  int e = blockIdx.x * 128 + w * 64 + lane;
  int2 sd = se[e];
  int dst = sd.y;
  const unsigned short* Ar = A2 + (size_t)dst * RSA;
  const unsigned char* Br = Bq + (size_t)sd.x * RSB;
  float invB = ((const float*)(Br + 248))[0];
  f32x4 acc[4][2];
  f32x4 zero = {0.f, 0.f, 0.f, 0.f};
#pragma unroll
  for (int rt = 0; rt < 4; rt++) {
    acc[rt][0] = zero;
    acc[rt][1] = zero;
  }
  gate_mfma(Ar, Br, invB, wmf, &Hs[w][0][0], lane, acc);
#pragma unroll
  for (int rt = 0; rt < 4; rt++) {
    int eb = rt * 16 + (lane >> 4) * 4;
    int ch = lane & 15;
#pragma unroll
    for (int r = 0; r < 4; r++) Ds[(eb + r) * 20 + ch] = acc[rt][0][r];
    if (ch < 4) {
#pragma unroll
      for (int r = 0; r < 4; r++) Ds[(eb + r) * 20 + 16 + ch] = acc[rt][1][r];
    }
  }
  // per-edge scalar contribution: dot(gate * xd, W2)
  float invXb = ((const float*)(Br + 248))[1];
  const __half* xtb = (const __half*)(Br + 208);
  const float* Ax = (const float*)(Ar + 208);
  unsigned wxb[10];
  {
    uint4 s0 = *(const uint4*)(xtb);
    uint4 s1 = *(const uint4*)(xtb + 8);
    uint2 s2 = *(const uint2*)(xtb + 16);
    wxb[0] = s0.x; wxb[1] = s0.y; wxb[2] = s0.z; wxb[3] = s0.w;
    wxb[4] = s1.x; wxb[5] = s1.y; wxb[6] = s1.z; wxb[7] = s1.w;
    wxb[8] = s2.x; wxb[9] = s2.y;
  }
  float sv = 0.f;
#pragma unroll
  for (int i = 0; i < 10; i++) {
    float2 gp = *(const float2*)&Ds[lane * 20 + 2 * i];
    float gx = gp.x + bm2[2 * i];
    float gy = gp.y + bm2[2 * i + 1];
    float2 xa = *(const float2*)(Ax + 2 * i);
    float2 fb = h2f(wxb[i]);
    sv += gx * (xa.x - fb.x * invXb) * W2[2 * i] +
          gy * (xa.y - fb.y * invXb) * W2[2 * i + 1];
  }
  // wave-level segmented sum over equal-dst runs (dst-sorted), 1 atomic/run
  bool seg[6];
#pragma unroll
  for (int i = 0; i < 6; i++) {
    int s = 1 << i;
    int od = __shfl_up(dst, s);
    seg[i] = (lane >= s) && (od == dst);
  }
#pragma unroll
  for (int i = 0; i < 6; i++) {
    float o = __shfl_up(sv, 1 << i);
    if (seg[i]) sv += o;
  }
  int dn = __shfl_down(dst, 1);
  bool is_last = (lane == 63) || (dn != dst);
  if (is_last) atomicAdd(out + dst, sv);
  // node-term fold: 8 nodes/block, grid 3125 = N/8
  if (tid < 8) {
    int n = blockIdx.x * 8 + tid;
    float deg = (float)(off[n + 1] - off[n]);
    float v = b1[0] + deg * b2[0];
    const float* xp = xrp + (size_t)n * 20;
#pragma unroll
    for (int c = 0; c < 20; c++) v += xp[c] * W1[c];
    atomicAdd(out + n, v);
  }
}

// afp1: after layer-d edge (gd 1-channel bf16). Per block: 8 nodes.
__global__ void __launch_bounds__(256) afp1_kernel(
    const unsigned short* __restrict__ gd, const int* __restrict__ off,
    const float* __restrict__ xrp,
    const float* __restrict__ W1, const float* __restrict__ b1,
    const float* __restrict__ W2, const float* __restrict__ b2,
    const float* __restrict__ Wm1n, const float* __restrict__ bm1n,
    unsigned short* __restrict__ A2, unsigned char* __restrict__ Bq,
    float* __restrict__ xrn) {
  __shared__ float ag[8], xp[8], degs[8];
  __shared__ float xv[8][21];
  __shared__ unsigned bmaxu[8];
  __shared__ float xmaxs[8];
  int tid = threadIdx.x;
  int n0 = blockIdx.x * 8;
  if (tid < 8) {
    bmaxu[tid] = 0;
    int n = n0 + tid;
    int s = off[n], t = off[n + 1];
    ag[tid] = seg_sum_bf16(gd, s, t);
    xp[tid] = xrp[n];
    degs[tid] = (float)(t - s);
  }
  __syncthreads();
  if (tid < 160) {
    int o = tid >> 3, nl = tid & 7;
    float v = b1[o] + degs[nl] * b2[o] + ag[nl] * W2[o] + xp[nl] * W1[o];
    float r = fmaxf(v, 0.f);
    xv[nl][o] = r;
    xrn[(n0 + nl) * 20 + o] = r;
  }
  __syncthreads();
  if (tid < 8) {
    float m = 0.f;
#pragma unroll
    for (int c = 0; c < 20; c++) m = fmaxf(m, xv[tid][c]);
    xmaxs[tid] = fmaxf(m, 1e-30f);
  }
  int k = tid;
  float aa[8], bb[8];
  if (k < KM) {
    v2f wab[20];
    float bm = bm1n[k];
#pragma unroll
    for (int c = 0; c < 20; c++) {
      wab[c].x = Wm1n[c * KM + k];
      wab[c].y = Wm1n[(20 + c) * KM + k];
    }
#pragma unroll
    for (int nl = 0; nl < 8; nl++) {
      v2f acc;
      acc.x = bm;
      acc.y = 0.f;
#pragma unroll
      for (int c = 0; c < 20; c++) {
        v2f xc;
        xc.x = xv[nl][c];
        xc.y = xv[nl][c];
        acc += xc * wab[c];
      }
      aa[nl] = acc.x;
      bb[nl] = acc.y;
    }
  }
  float mxb[8];
#pragma unroll
  for (int nl = 0; nl < 8; nl++) mxb[nl] = (k < KM) ? fabsf(bb[nl]) : 0.f;
#pragma unroll
  for (int s = 1; s < 64; s <<= 1) {
#pragma unroll
    for (int nl = 0; nl < 8; nl++) mxb[nl] = fmaxf(mxb[nl], __shfl_xor(mxb[nl], s));
  }
  if ((tid & 63) == 0) {
#pragma unroll
    for (int nl = 0; nl < 8; nl++) atomicMax(&bmaxu[nl], __float_as_uint(mxb[nl]));
  }
  __syncthreads();
  if (k < KM) {
#pragma unroll
    for (int nl = 0; nl < 8; nl++) {
      float bmax = fmaxf(__uint_as_float(bmaxu[nl]), 1e-30f);
      float xmax = xmaxs[nl];
      unsigned short* Au = A2 + (size_t)(n0 + nl) * RSA;
      unsigned char* rb = Bq + (size_t)(n0 + nl) * RSB;
      Au[k] = f2bfr(aa[nl]);
      rb[k] = (unsigned char)(signed char)lrintf(bb[nl] * (127.f / bmax));
      if (k < 20) {
        ((float*)(Au + 208))[k] = xv[nl][k];
        ((__half*)(rb + 208))[k] = __float2half(xv[nl][k] * (32768.f / xmax));
      }
      if (k == 0) {
        ((float*)(rb + 248))[0] = bmax / 127.f;
        ((float*)(rb + 248))[1] = xmax / 32768.f;
      }
    }
  }
}

// afp20: after a hidden edge (gd 20-channel bf16). Same 3 phases, CIN=20.
__global__ void __launch_bounds__(256) afp20_kernel(
    const unsigned short* __restrict__ gd, const int* __restrict__ off,
    const float* __restrict__ xrp,
    const float* __restrict__ W1, const float* __restrict__ b1,
    const float* __restrict__ W2, const float* __restrict__ b2,
    const float* __restrict__ Wm1n, const float* __restrict__ bm1n,
    unsigned short* __restrict__ A2, unsigned char* __restrict__ Bq,
    float* __restrict__ xrn) {
  __shared__ float ag[8][21], xp[8][21], xv[8][21], degs[8];
  __shared__ unsigned bmaxu[8];
  __shared__ float xmaxs[8];
  int tid = threadIdx.x;
  int n0 = blockIdx.x * 8;
  if (tid < 8) bmaxu[tid] = 0;
  if (tid < 160) {
    int c = tid >> 3, nl = tid & 7;
    int n = n0 + nl;
    int s = off[n], t = off[n + 1];
    ag[nl][c] = seg_sum_bf16(gd + (size_t)c * E_EDGES, s, t);
    xp[nl][c] = xrp[n * 20 + c];
    if (c == 0) degs[nl] = (float)(t - s);
  }
  __syncthreads();
  if (tid < 160) {
    int o = tid >> 3, nl = tid & 7;
    float v = b1[o] + degs[nl] * b2[o];
#pragma unroll
    for (int c = 0; c < 20; c++) {
      v += ag[nl][c] * W2[c * 20 + o] + xp[nl][c] * W1[c * 20 + o];
    }
    float r = fmaxf(v, 0.f);
    xv[nl][o] = r;
    xrn[(n0 + nl) * 20 + o] = r;
  }
  __syncthreads();
  if (tid < 8) {
    float m = 0.f;
#pragma unroll
    for (int c = 0; c < 20; c++) m = fmaxf(m, xv[tid][c]);
    xmaxs[tid] = fmaxf(m, 1e-30f);
  }
  int k = tid;
  float aa[8], bb[8];
  if (k < KM) {
    v2f wab[20];
    float bm = bm1n[k];
#pragma unroll
    for (int c = 0; c < 20; c++) {
      wab[c].x = Wm1n[c * KM + k];
      wab[c].y = Wm1n[(20 + c) * KM + k];
    }
#pragma unroll
    for (int nl = 0; nl < 8; nl++) {
      v2f acc;
      acc.x = bm;
      acc.y = 0.f;
#pragma unroll
      for (int c = 0; c < 20; c++) {
        v2f xc;
        xc.x = xv[nl][c];
        xc.y = xv[nl][c];
        acc += xc * wab[c];
      }
      aa[nl] = acc.x;
      bb[nl] = acc.y;
    }
  }
  float mxb[8];
#pragma unroll
  for (int nl = 0; nl < 8; nl++) mxb[nl] = (k < KM) ? fabsf(bb[nl]) : 0.f;
#pragma unroll
  for (int s = 1; s < 64; s <<= 1) {
#pragma unroll
    for (int nl = 0; nl < 8; nl++) mxb[nl] = fmaxf(mxb[nl], __shfl_xor(mxb[nl], s));
  }
  if ((tid & 63) == 0) {
#pragma unroll
    for (int nl = 0; nl < 8; nl++) atomicMax(&bmaxu[nl], __float_as_uint(mxb[nl]));
  }
  __syncthreads();
  if (k < KM) {
#pragma unroll
    for (int nl = 0; nl < 8; nl++) {
      float bmax = fmaxf(__uint_as_float(bmaxu[nl]), 1e-30f);
      float xmax = xmaxs[nl];
      unsigned short* Au = A2 + (size_t)(n0 + nl) * RSA;
      unsigned char* rb = Bq + (size_t)(n0 + nl) * RSB;
      Au[k] = f2bfr(aa[nl]);
      rb[k] = (unsigned char)(signed char)lrintf(bb[nl] * (127.f / bmax));
      if (k < 20) {
        ((float*)(Au + 208))[k] = xv[nl][k];
        ((__half*)(rb + 208))[k] = __float2half(xv[nl][k] * (32768.f / xmax));
      }
      if (k == 0) {
        ((float*)(rb + 248))[0] = bmax / 127.f;
        ((float*)(rb + 248))[1] = xmax / 32768.f;
      }
    }
  }
}

// ---------------- launch ----------------

extern "C" void kernel_launch(void* const* d_in, const int* in_sizes, int n_in,
                              void* d_out, int out_size, void* d_ws, size_t ws_size,
                              hipStream_t stream) {
  const float* features = (const float*)d_in[0];
  const int* edges = (const int*)d_in[1];
  // d_in[2] = weights (unused by reference)

  const float *dW1 = (const float*)d_in[3], *db1 = (const float*)d_in[4],
              *dWm1 = (const float*)d_in[5], *dbm1 = (const float*)d_in[6],
              *dWm2 = (const float*)d_in[7], *dbm2 = (const float*)d_in[8],
              *dW2 = (const float*)d_in[9], *db2 = (const float*)d_in[10];
  const float *hW1 = (const float*)d_in[11], *hb1 = (const float*)d_in[12],
              *hWm1 = (const float*)d_in[13], *hbm1 = (const float*)d_in[14],
              *hWm2 = (const float*)d_in[15], *hbm2 = (const float*)d_in[16],
              *hW2 = (const float*)d_in[17], *hb2 = (const float*)d_in[18];
  const float *oW1 = (const float*)d_in[19], *ob1 = (const float*)d_in[20],
              *oWm1 = (const float*)d_in[21], *obm1 = (const float*)d_in[22],
              *oWm2 = (const float*)d_in[23], *obm2 = (const float*)d_in[24],
              *oW2 = (const float*)d_in[25], *ob2 = (const float*)d_in[26];

  // workspace layout (float units)
  float* fws = (float*)d_ws;
  size_t o = 0;
  unsigned short* A2 = (unsigned short*)(fws + o); o += (size_t)N_NODES * (RSA / 2);
  unsigned char* Bq = (unsigned char*)(fws + o);   o += (size_t)N_NODES * RSB / 4;
  unsigned short* gd = (unsigned short*)(fws + o); o += (size_t)20 * E_EDGES / 2;
  float* xrA = fws + o;                            o += (size_t)N_NODES * 20;
  float* xrB = fws + o;                            o += (size_t)N_NODES * 20;
  u16x8* wmfh = (u16x8*)(fws + o);                 o += 3584;  // 896 * 16 B
  u16x8* wmfo = (u16x8*)(fws + o);                 o += 3584;
  int* ip = (int*)(fws + o);
  int* hist = ip;   ip += N_NODES;
  int* off = ip;    ip += N_NODES + 4;
  int* cursor = ip; ip += N_NODES;
  int* bsum = ip;   ip += 32;
  int* boff = ip;   ip += 32;
  int2* se = (int2*)ip;

  const int B256 = 256;
  const int EDGE_G = E_EDGES / 128;  // 3125, exact
  const int NODE8_G = N_NODES / 8;   // 3125, exact

  // build dst-sorted edge list + CSR offsets (recomputed every launch)
  (void)hipMemsetAsync(hist, 0, N_NODES * sizeof(int), stream);
  hist_kernel<<<(E_EDGES + B256 - 1) / B256, B256, 0, stream>>>(edges, hist);
  hist_bsum_kernel<<<SCB, 1024, 0, stream>>>(hist, bsum);
  scan_tiny_kernel<<<1, 1024, 0, stream>>>(bsum, boff, hWm2, oWm2, wmfh, wmfo);
  scan_fill_kernel<<<SCB, 1024, 0, stream>>>(hist, boff, off, cursor);

  // layer d: 1 -> 20 (scatter + d_out zeroing fused into prep)
  scatter_prep_d_kernel<<<NODE8_G, B256, 0, stream>>>(edges, cursor, se, features,
                                                      dWm1, dbm1, A2, Bq, xrA,
                                                      (float*)d_out);
  edge1_kernel<<<EDGE_G, 128, 0, stream>>>(se, A2, Bq, dWm2, dbm2, gd);
  afp1_kernel<<<NODE8_G, B256, 0, stream>>>(gd, off, xrA, dW1, db1, dW2, db2,
                                            hWm1, hbm1, A2, Bq, xrB);

  // hidden1
  edge_mfma20_kernel<<<EDGE_G, 128, 0, stream>>>(se, A2, Bq, wmfh, hbm2, gd);
  afp20_kernel<<<NODE8_G, B256, 0, stream>>>(gd, off, xrB, hW1, hb1, hW2, hb2,
                                             hWm1, hbm1, A2, Bq, xrA);
  // hidden2
  edge_mfma20_kernel<<<EDGE_G, 128, 0, stream>>>(se, A2, Bq, wmfh, hbm2, gd);
  afp20_kernel<<<NODE8_G, B256, 0, stream>>>(gd, off, xrA, hW1, hb1, hW2, hb2,
                                             hWm1, hbm1, A2, Bq, xrB);
  // hidden3 -> preps output layer (oWm1)
  edge_mfma20_kernel<<<EDGE_G, 128, 0, stream>>>(se, A2, Bq, wmfh, hbm2, gd);
  afp20_kernel<<<NODE8_G, B256, 0, stream>>>(gd, off, xrB, hW1, hb1, hW2, hb2,
                                             oWm1, obm1, A2, Bq, xrA);
  // output layer: 20 -> 1, gd-free (scalar atomics into d_out) + node terms fused
  edge_final_mfma_kernel<<<EDGE_G, 128, 0, stream>>>(se, A2, Bq, wmfo, obm2, oW2,
                                                     off, xrA, oW1, ob1, ob2,
                                                     (float*)d_out);
}